// Round 2
// baseline (1141.439 us; speedup 1.0000x reference)
//
#include <hip/hip_runtime.h>

#define N_SRC   100000
#define N_DST   100000
#define N_EDGES 1250000
#define D_FEAT  64
#define HIDDEN  64
#define OUT_F   128

// ---------------------------------------------------------------------------
// Kernel 1: hs = relu(h_src @ W1 + b1)   [N_SRC, 64]
// One wave per row: lane j computes output j. W1 staged in LDS (16 KB).
// ---------------------------------------------------------------------------
__global__ __launch_bounds__(256) void fc1_kernel(
        const float* __restrict__ h_src, const float* __restrict__ W1,
        const float* __restrict__ b1, float* __restrict__ hs) {
    __shared__ float W1s[D_FEAT * HIDDEN];
    for (int i = threadIdx.x; i < D_FEAT * HIDDEN; i += 256) W1s[i] = W1[i];
    __syncthreads();
    const int lane = threadIdx.x & 63;
    const int wid  = threadIdx.x >> 6;
    const int row  = blockIdx.x * 4 + wid;
    if (row >= N_SRC) return;
    float x   = h_src[row * D_FEAT + lane];
    float acc = b1[lane];
    #pragma unroll
    for (int k = 0; k < D_FEAT; ++k) {
        float a = __shfl(x, k, 64);
        acc = fmaf(a, W1s[k * HIDDEN + lane], acc);
    }
    hs[row * HIDDEN + lane] = fmaxf(acc, 0.0f);
}

// ---------------------------------------------------------------------------
// Kernel 2: edge scatter.  One wave per edge (grid-stride).
// lane k: vs[dst][k] += hs[src][k] * w   (coalesced 256B gather + atomics)
// ---------------------------------------------------------------------------
__global__ __launch_bounds__(256) void edge_kernel(
        const float* __restrict__ hs, const float* __restrict__ ew,
        const int* __restrict__ src, const int* __restrict__ dst,
        float* __restrict__ vs, float* __restrict__ wsum) {
    const int lane = threadIdx.x & 63;
    const int wid  = blockIdx.x * 4 + (threadIdx.x >> 6);
    const int stride = gridDim.x * 4;
    for (int e = wid; e < N_EDGES; e += stride) {
        int   s = src[e];
        int   d = dst[e];
        float w = ew[e];
        float val = hs[s * HIDDEN + lane] * w;
        atomicAdd(&vs[d * HIDDEN + lane], val);
        if (lane == 0) atomicAdd(&wsum[d], w);
    }
}

// ---------------------------------------------------------------------------
// Kernel 3 (REWRITTEN): new = relu(concat([vs/max(wsum,1), h_dst]) @ W2 + b2)
// Weights-in-registers: each wave owns one 64-column half of W2 as a
// statically-indexed 128-float register array (no LDS, ~150 VGPR).
// Wave w handles half = w&1, grid-strides rows by nWaves/2. Input row is
// broadcast from 2 lane-registers via __shfl; 4 partial accumulators break
// the FMA dependency chain. One double atomicAdd per wave for sum-of-squares.
// ---------------------------------------------------------------------------
__global__ __launch_bounds__(256, 3) void fc2_kernel(
        const float* __restrict__ vs, const float* __restrict__ wsum,
        const float* __restrict__ h_dst, const float* __restrict__ W2,
        const float* __restrict__ b2, float* __restrict__ out,
        double* __restrict__ sumsq) {
    const int lane = threadIdx.x & 63;
    const int gwid = blockIdx.x * 4 + (threadIdx.x >> 6);
    const int half = gwid & 1;
    const int col  = half * 64 + lane;          // this lane's output column

    float wcol[HIDDEN + D_FEAT];                // W2[:, col] — stays in VGPRs
    #pragma unroll
    for (int k = 0; k < HIDDEN + D_FEAT; ++k) wcol[k] = W2[k * OUT_F + col];
    const float bias = b2[col];

    double ss = 0.0;
    const int rowStride = (gridDim.x * 4) >> 1;
    for (int row = gwid >> 1; row < N_DST; row += rowStride) {
        float winv = 1.0f / fmaxf(wsum[row], 1.0f);
        float x0 = vs[row * HIDDEN + lane] * winv;
        float x1 = h_dst[row * D_FEAT + lane];
        float a0 = bias, a1 = 0.0f, a2 = 0.0f, a3 = 0.0f;
        #pragma unroll
        for (int k = 0; k < HIDDEN; k += 4) {
            a0 = fmaf(__shfl(x0, k,     64), wcol[k],     a0);
            a1 = fmaf(__shfl(x0, k + 1, 64), wcol[k + 1], a1);
            a2 = fmaf(__shfl(x0, k + 2, 64), wcol[k + 2], a2);
            a3 = fmaf(__shfl(x0, k + 3, 64), wcol[k + 3], a3);
        }
        #pragma unroll
        for (int k = 0; k < D_FEAT; k += 4) {
            a0 = fmaf(__shfl(x1, k,     64), wcol[HIDDEN + k],     a0);
            a1 = fmaf(__shfl(x1, k + 1, 64), wcol[HIDDEN + k + 1], a1);
            a2 = fmaf(__shfl(x1, k + 2, 64), wcol[HIDDEN + k + 2], a2);
            a3 = fmaf(__shfl(x1, k + 3, 64), wcol[HIDDEN + k + 3], a3);
        }
        float v = fmaxf((a0 + a1) + (a2 + a3), 0.0f);
        out[row * OUT_F + col] = v;
        ss += (double)v * (double)v;
    }
    #pragma unroll
    for (int off = 32; off > 0; off >>= 1) ss += __shfl_down(ss, off, 64);
    if (lane == 0) atomicAdd(sumsq, ss);
}

// ---------------------------------------------------------------------------
// Kernel 4: out *= 1/sqrt(sumsq)   (in-place, float4 grid-stride)
// ---------------------------------------------------------------------------
__global__ __launch_bounds__(256) void scale_kernel(
        float* __restrict__ out, const double* __restrict__ sumsq, int n4) {
    const float s = (float)(1.0 / sqrt(*sumsq));
    float4* o4 = (float4*)out;
    const int stride = gridDim.x * blockDim.x;
    for (int i = blockIdx.x * blockDim.x + threadIdx.x; i < n4; i += stride) {
        float4 v = o4[i];
        v.x *= s; v.y *= s; v.z *= s; v.w *= s;
        o4[i] = v;
    }
}

extern "C" void kernel_launch(void* const* d_in, const int* in_sizes, int n_in,
                              void* d_out, int out_size, void* d_ws, size_t ws_size,
                              hipStream_t stream) {
    const float* h_src = (const float*)d_in[0];
    const float* h_dst = (const float*)d_in[1];
    const float* ew    = (const float*)d_in[2];
    const float* W1    = (const float*)d_in[3];
    const float* b1    = (const float*)d_in[4];
    const float* W2    = (const float*)d_in[5];
    const float* b2    = (const float*)d_in[6];
    const int*   src   = (const int*)d_in[7];
    const int*   dst   = (const int*)d_in[8];
    float* out = (float*)d_out;

    // Scratch layout:
    //   d_out[0 .. 6.4M floats)  : hs (reused; fc2 overwrites all of d_out later)
    //   d_ws + 0                 : vs    [N_DST * 64] f32   (25.6 MB)
    //   d_ws + 25,600,000        : wsum  [N_DST]      f32   (0.4 MB)
    //   d_ws + 26,000,000        : sumsq [1]          f64
    float*  hs    = out;
    float*  vs    = (float*)d_ws;
    float*  wsum  = (float*)((char*)d_ws + (size_t)N_DST * HIDDEN * 4);
    double* sumsq = (double*)((char*)d_ws + (size_t)N_DST * HIDDEN * 4 + (size_t)N_DST * 4);

    hipMemsetAsync(d_ws, 0, (size_t)N_DST * HIDDEN * 4 + (size_t)N_DST * 4 + 8, stream);

    fc1_kernel<<<(N_SRC + 3) / 4, 256, 0, stream>>>(h_src, W1, b1, hs);
    edge_kernel<<<4096, 256, 0, stream>>>(hs, ew, src, dst, vs, wsum);
    fc2_kernel<<<1024, 256, 0, stream>>>(vs, wsum, h_dst, W2, b2, out, sumsq);
    scale_kernel<<<2048, 256, 0, stream>>>(out, sumsq, N_DST * OUT_F / 4);
}

// Round 3
// 729.172 us; speedup vs baseline: 1.5654x; 1.5654x over previous
//
#include <hip/hip_runtime.h>

#define N_SRC   100000
#define N_DST   100000
#define N_EDGES 1250000
#define D_FEAT  64
#define HIDDEN  64
#define OUT_F   128

// ---------------------------------------------------------------------------
// Kernel 1: hs = relu(h_src @ W1 + b1)   [N_SRC, 64]
// One wave per row: lane j computes output j. W1 staged in LDS (16 KB).
// ---------------------------------------------------------------------------
__global__ __launch_bounds__(256) void fc1_kernel(
        const float* __restrict__ h_src, const float* __restrict__ W1,
        const float* __restrict__ b1, float* __restrict__ hs) {
    __shared__ float W1s[D_FEAT * HIDDEN];
    for (int i = threadIdx.x; i < D_FEAT * HIDDEN; i += 256) W1s[i] = W1[i];
    __syncthreads();
    const int lane = threadIdx.x & 63;
    const int wid  = threadIdx.x >> 6;
    const int row  = blockIdx.x * 4 + wid;
    if (row >= N_SRC) return;
    float x   = h_src[row * D_FEAT + lane];
    float acc = b1[lane];
    #pragma unroll
    for (int k = 0; k < D_FEAT; ++k) {
        float a = __shfl(x, k, 64);
        acc = fmaf(a, W1s[k * HIDDEN + lane], acc);
    }
    hs[row * HIDDEN + lane] = fmaxf(acc, 0.0f);
}

// ---------------------------------------------------------------------------
// Kernel 2: edge scatter.  One wave per edge (grid-stride).
// lane k: vs[dst][k] += hs[src][k] * w   (coalesced 256B gather + atomics)
// ---------------------------------------------------------------------------
__global__ __launch_bounds__(256) void edge_kernel(
        const float* __restrict__ hs, const float* __restrict__ ew,
        const int* __restrict__ src, const int* __restrict__ dst,
        float* __restrict__ vs, float* __restrict__ wsum) {
    const int lane = threadIdx.x & 63;
    const int wid  = blockIdx.x * 4 + (threadIdx.x >> 6);
    const int stride = gridDim.x * 4;
    for (int e = wid; e < N_EDGES; e += stride) {
        int   s = src[e];
        int   d = dst[e];
        float w = ew[e];
        float val = hs[s * HIDDEN + lane] * w;
        atomicAdd(&vs[d * HIDDEN + lane], val);
        if (lane == 0) atomicAdd(&wsum[d], w);
    }
}

// ---------------------------------------------------------------------------
// Kernel 3 (REWRITTEN again): new = relu(concat([vs/max(wsum,1), h_dst]) @ W2 + b2)
// Split work across the block's 4 waves as (col-half ch, k-half kh).
// Each wave holds wcol[64] = W2[kh*64 .. kh*64+63][ch*64+lane] in VGPRs
// (64 floats/lane — small enough that the allocator provably keeps it;
// round-2's 128-float version was sunk into the loop -> 10x over-fetch).
// 8 rows per round: x-row loaded once, __shfl broadcast, 4 acc chains;
// partials combined through an 8 KB LDS buffer (+bias, relu, store, ss).
// ---------------------------------------------------------------------------
__global__ __launch_bounds__(256) void fc2_kernel(
        const float* __restrict__ vs, const float* __restrict__ wsum,
        const float* __restrict__ h_dst, const float* __restrict__ W2,
        const float* __restrict__ b2, float* __restrict__ out,
        double* __restrict__ sumsq) {
    __shared__ float P[8 * 2 * 128];          // [row r][k-half][col], 8 KiB
    const int lane = threadIdx.x & 63;
    const int wid  = threadIdx.x >> 6;
    const int ch   = wid & 1;                 // column half (0: cols 0-63, 1: 64-127)
    const int kh   = wid >> 1;                // k half (0: vs part, 1: h_dst part)
    const float* __restrict__ xsrc = kh ? h_dst : vs;   // both [*, 64] row-major

    float wcol[64];                           // W2[kh*64+kk][ch*64+lane]
    #pragma unroll
    for (int kk = 0; kk < 64; ++kk)
        wcol[kk] = W2[(kh * 64 + kk) * OUT_F + ch * 64 + lane];

    const float bias = b2[threadIdx.x & 127];
    double ss = 0.0;

    const int NG = N_DST / 8;                 // 12500 groups of 8 rows
    for (int g = blockIdx.x; g < NG; g += gridDim.x) {
        const int base = g * 8;
        float xr[8];
        #pragma unroll
        for (int r = 0; r < 8; ++r)
            xr[r] = xsrc[(base + r) * 64 + lane];
        if (kh == 0) {
            #pragma unroll
            for (int r = 0; r < 8; ++r)
                xr[r] *= 1.0f / fmaxf(wsum[base + r], 1.0f);
        }
        #pragma unroll
        for (int r = 0; r < 8; ++r) {
            float a0 = 0.f, a1 = 0.f, a2 = 0.f, a3 = 0.f;
            #pragma unroll
            for (int kk = 0; kk < 64; kk += 4) {
                a0 = fmaf(__shfl(xr[r], kk,     64), wcol[kk],     a0);
                a1 = fmaf(__shfl(xr[r], kk + 1, 64), wcol[kk + 1], a1);
                a2 = fmaf(__shfl(xr[r], kk + 2, 64), wcol[kk + 2], a2);
                a3 = fmaf(__shfl(xr[r], kk + 3, 64), wcol[kk + 3], a3);
            }
            P[r * 256 + kh * 128 + ch * 64 + lane] = (a0 + a1) + (a2 + a3);
        }
        __syncthreads();
        #pragma unroll
        for (int v = 0; v < 4; ++v) {
            int idx = v * 256 + (int)threadIdx.x;
            int row = idx >> 7, col = idx & 127;
            float s = P[row * 256 + col] + P[row * 256 + 128 + col] + bias;
            float val = fmaxf(s, 0.0f);
            out[(base + row) * OUT_F + col] = val;
            ss += (double)val * (double)val;
        }
        __syncthreads();                      // WAR: P overwritten next round
    }
    #pragma unroll
    for (int off = 32; off > 0; off >>= 1) ss += __shfl_down(ss, off, 64);
    if (lane == 0) atomicAdd(sumsq, ss);
}

// ---------------------------------------------------------------------------
// Kernel 4: out *= 1/sqrt(sumsq)   (in-place, float4 grid-stride)
// ---------------------------------------------------------------------------
__global__ __launch_bounds__(256) void scale_kernel(
        float* __restrict__ out, const double* __restrict__ sumsq, int n4) {
    const float s = (float)(1.0 / sqrt(*sumsq));
    float4* o4 = (float4*)out;
    const int stride = gridDim.x * blockDim.x;
    for (int i = blockIdx.x * blockDim.x + threadIdx.x; i < n4; i += stride) {
        float4 v = o4[i];
        v.x *= s; v.y *= s; v.z *= s; v.w *= s;
        o4[i] = v;
    }
}

extern "C" void kernel_launch(void* const* d_in, const int* in_sizes, int n_in,
                              void* d_out, int out_size, void* d_ws, size_t ws_size,
                              hipStream_t stream) {
    const float* h_src = (const float*)d_in[0];
    const float* h_dst = (const float*)d_in[1];
    const float* ew    = (const float*)d_in[2];
    const float* W1    = (const float*)d_in[3];
    const float* b1    = (const float*)d_in[4];
    const float* W2    = (const float*)d_in[5];
    const float* b2    = (const float*)d_in[6];
    const int*   src   = (const int*)d_in[7];
    const int*   dst   = (const int*)d_in[8];
    float* out = (float*)d_out;

    // Scratch layout:
    //   d_out[0 .. 6.4M floats)  : hs (reused; fc2 overwrites all of d_out later)
    //   d_ws + 0                 : vs    [N_DST * 64] f32   (25.6 MB)
    //   d_ws + 25,600,000        : wsum  [N_DST]      f32   (0.4 MB)
    //   d_ws + 26,000,000        : sumsq [1]          f64
    float*  hs    = out;
    float*  vs    = (float*)d_ws;
    float*  wsum  = (float*)((char*)d_ws + (size_t)N_DST * HIDDEN * 4);
    double* sumsq = (double*)((char*)d_ws + (size_t)N_DST * HIDDEN * 4 + (size_t)N_DST * 4);

    hipMemsetAsync(d_ws, 0, (size_t)N_DST * HIDDEN * 4 + (size_t)N_DST * 4 + 8, stream);

    fc1_kernel<<<(N_SRC + 3) / 4, 256, 0, stream>>>(h_src, W1, b1, hs);
    edge_kernel<<<4096, 256, 0, stream>>>(hs, ew, src, dst, vs, wsum);
    fc2_kernel<<<1024, 256, 0, stream>>>(vs, wsum, h_dst, W2, b2, out, sumsq);
    scale_kernel<<<2048, 256, 0, stream>>>(out, sumsq, N_DST * OUT_F / 4);
}